// Round 4
// baseline (10.522 us; speedup 1.0000x reference)
//
#include <hip/hip_runtime.h>

// diffNet closed-form, branchless, divide-free, 4 particles/thread.
// 128 steps of v' = v + DT*lerp(force, v); x += DT*v', plus initial x += DT*v.
// force in [0,1], DT=1e-3 => total v growth <= 0.128 => floor(v) crosses at
// most one integer boundary. Per segment v' = a*v + b (affine) -> closed form.
// Interpolant is continuous at the boundary, so +-1 error in the crossing
// step count T0 is a second-order (~1e-6) error.
//
// Stable series (h = DT*B, |h| <= 1e-3; |u| <= 0.13):
//   psi(h)    = log1p(h)/h   ~ 1 - h/2 + h^2/3
//   L         = h*psi (= log a)
//   phi(u)    = expm1(u)/u   ~ 1 + u/2 + u^2/6 + u^3/24 + u^4/120
//   invphi(u) = u/expm1(u)   ~ 1 - u/2 + u^2/12        (Bernoulli)
//   v_T = v0 + g*T*phi(T*L),  g = f(v0)*DT*psi
//   sum_{k=1..T} v_k = T*v0 + g*(s1 + L*s2/2 + L^2*s3/6 + L^3*s4/24)
// Crossing solve: one v_rcp_f32 + two invphi refinements, clamped to [1,128]
// (absorbs the no-crossing case via rcp(0)=+inf).
//
// R4: 4 independent particles per thread (2x float4 load/store) to deepen
// per-wave memory pipelining and give 4 independent FMA chains for latency
// hiding. Discriminates latency-bound vs fixed-overhead-floor.

constexpr float DT = 0.001f;
constexpr float TS = 128.0f;

__device__ __forceinline__ float phi5(float u) {          // expm1(u)/u
    return 1.0f + u*(0.5f + u*((1.0f/6.0f) + u*((1.0f/24.0f) + u*(1.0f/120.0f))));
}
__device__ __forceinline__ float invphi(float u) {        // u/expm1(u)
    return 1.0f + u*(-0.5f + u*(1.0f/12.0f));
}
__device__ __forceinline__ float sig(float T, float L) {  // sum_{k=1..T} k*phi(kL)
    float s1 = 0.5f*T*(T+1.0f);
    float s2 = s1*(2.0f*T+1.0f)*(1.0f/3.0f);
    float s3 = s1*s1;
    float s4 = s2*fmaf(3.0f*T, T+1.0f, -1.0f)*(1.0f/5.0f);
    return s1 + L*(0.5f*s2 + L*((1.0f/6.0f)*s3 + (1.0f/24.0f)*L*s4));
}

__device__ __forceinline__ float2 integrate(float x, float v,
                                            const float* __restrict__ sf)
{
    x = fmaf(DT, v, x);                 // pre-loop x update (original v)

    float fl = floorf(v);
    int   i0 = (int)fl;
    float F0 = sf[i0];
    float F1 = sf[min(i0 + 1, 256)];
    float F2 = sf[min(i0 + 2, 256)];

    float B0 = F1 - F0;                 // seg0: f = A0 + B0*v
    float A0 = fmaf(-fl, B0, F0);
    float B1 = F2 - F1;                 // seg1: f = A1 + B1*v
    float A1 = fmaf(-(fl + 1.0f), B1, F1);

    // segment-0 dynamics
    float f0   = fmaf(B0, v, A0);       // >= 0
    float h0   = DT * B0;
    float psi0 = 1.0f + h0*(-0.5f + h0*(1.0f/3.0f));
    float L0   = h0 * psi0;
    float g0   = f0 * (DT * psi0);      // >= 0

    // crossing solve: k*phi(k*L0) = delta/g0, branchless
    float delta = (fl + 1.0f) - v;      // in (0,1]
    float r  = delta * __builtin_amdgcn_rcpf(g0);   // may be +inf (g0==0)
    float k  = fminf(r, 129.0f);
    k = fminf(r * invphi(k * L0), 129.0f);
    k = fminf(r * invphi(k * L0), 129.0f);
    float T0 = fminf(fmaxf(ceilf(k), 1.0f), TS);    // no-crossing -> 128

    // phase A: T0 steps under segment-0 dynamics
    float dvA = g0 * T0 * phi5(T0 * L0);
    float SA  = fmaf(T0, v, g0 * sig(T0, L0));
    float vA  = v + dvA;

    // phase B: remaining T1 steps under segment-1 dynamics (T1 may be 0)
    float T1   = TS - T0;
    float f1v  = fmaf(B1, vA, A1);
    float h1   = DT * B1;
    float psi1 = 1.0f + h1*(-0.5f + h1*(1.0f/3.0f));
    float L1   = h1 * psi1;
    float g1   = f1v * (DT * psi1);
    float dvB  = g1 * T1 * phi5(T1 * L1);
    float SB   = fmaf(T1, vA, g1 * sig(T1, L1));

    return make_float2(fmaf(DT, SA + SB, x), vA + dvB);
}

__global__ __launch_bounds__(256)
void diffnet_kernel(const float4* __restrict__ X,
                    const float*  __restrict__ force,
                    float4*       __restrict__ out,
                    int half)    // half = total float4 count / 2
{
    __shared__ float sf[257];
    int tid = threadIdx.x;
    sf[tid] = force[tid];
    if (tid == 0) sf[256] = force[256];
    __syncthreads();

    int j = blockIdx.x * blockDim.x + tid;
    if (j >= half) return;

    // two coalesced 16B loads -> 4 independent particles
    float4 s0 = X[j];
    float4 s1 = X[j + half];

    float2 r0 = integrate(s0.x, s0.y, sf);
    float2 r1 = integrate(s0.z, s0.w, sf);
    float2 r2 = integrate(s1.x, s1.y, sf);
    float2 r3 = integrate(s1.z, s1.w, sf);

    out[j]        = make_float4(r0.x, r0.y, r1.x, r1.y);
    out[j + half] = make_float4(r2.x, r2.y, r3.x, r3.y);
}

extern "C" void kernel_launch(void* const* d_in, const int* in_sizes, int n_in,
                              void* d_out, int out_size, void* d_ws, size_t ws_size,
                              hipStream_t stream)
{
    const float4* X     = (const float4*)d_in[0];   // (B,2) -> 2 particles/float4
    const float*  force = (const float*)d_in[1];    // 257 floats
    float4*       out   = (float4*)d_out;

    int nquads = in_sizes[0] / 4;       // B=1048576 -> 524288 float4s
    int half   = nquads / 2;            // 262144 threads, 4 particles each
    int block  = 256;
    int grid   = (half + block - 1) / block;

    diffnet_kernel<<<grid, block, 0, stream>>>(X, force, out, half);
}